// Round 3
// baseline (213.625 us; speedup 1.0000x reference)
//
#include <hip/hip_runtime.h>

#define B_TOTAL 2048
#define CAST    128
#define HDIM    256
#define INDIM   256
#define BM      8
#define GRU_BLOCKS (B_TOTAL / BM)     // 256
#define ROW_F4     (CAST * HDIM / 4)  // 8192 float4 per batch row

// ---------------- tables init ----------------
__global__ __launch_bounds__(256) void k_init(int* rowaid, int* rowstop) {
    int t = blockIdx.x * blockDim.x + threadIdx.x;
    if (t < B_TOTAL) { rowaid[t] = -1; rowstop[t] = 0; }
}

// ---------------- fill tables + transpose weights ----------------
// blocks 0..7: fill rowaid/rowstop. blocks 8..391: pack weights as
// wt[((k4*3 + gate)*256 + h)*4 + j] = w[(gate*256 + h)*256 + k4*4 + j]
__global__ __launch_bounds__(256) void k_prep(
    const int* __restrict__ batch_idxs, const int* __restrict__ actor_ids,
    const int* __restrict__ story_stop, int n_stop,
    const float* __restrict__ w_ih, const float* __restrict__ w_hh,
    int* rowaid, int* rowstop, float* wtI, float* wtH) {
    const int h = threadIdx.x;
    if (blockIdx.x < 8) {
        int t = blockIdx.x * 256 + h;
        int row = batch_idxs[t];
        int a = actor_ids[row];
        a = a < 0 ? 0 : (a > CAST - 1 ? CAST - 1 : a);
        rowaid[row] = a;
        if (t < n_stop) rowstop[story_stop[t]] = 1;
    } else {
        int id  = blockIdx.x - 8;          // 0..383
        int mat = id / 192;                // 0: w_ih, 1: w_hh
        int rem = id % 192;
        int g   = rem / 64;
        int k4  = rem % 64;
        const float* w = mat ? w_hh : w_ih;
        float*      wt = mat ? wtH  : wtI;
        float4 wv = *(const float4*)(w + ((size_t)(g * HDIM + h) * INDIM + k4 * 4));
        *(float4*)(wt + ((size_t)((k4 * 3 + g) * HDIM + h)) * 4) = wv;
    }
}

// ---------------- GRU on the 2048 gathered rows ----------------
__global__ __launch_bounds__(256) void k_gru(
    const float* __restrict__ x, const int* __restrict__ batch_idxs,
    const int* __restrict__ actor_ids, const float* __restrict__ state,
    const float* __restrict__ wtI, const float* __restrict__ wtH,
    const float* __restrict__ b_ih, const float* __restrict__ b_hh,
    const int* __restrict__ rowstop,
    float* __restrict__ out_sel, float* __restrict__ out_state) {
    __shared__ float xs[BM][INDIM];
    __shared__ float ss[BM][HDIM];
    const int h  = threadIdx.x;
    const int b0 = blockIdx.x * BM;

    #pragma unroll
    for (int r = 0; r < BM; ++r) {
        int g  = b0 + r;
        int bi = batch_idxs[g];
        int a  = actor_ids[bi];
        a = a < 0 ? 0 : (a > CAST - 1 ? CAST - 1 : a);
        xs[r][h] = x[(size_t)g * INDIM + h];
        ss[r][h] = state[((size_t)bi * CAST + a) * HDIM + h];
    }
    __syncthreads();

    float air[BM], aiz[BM], ain[BM], ahr[BM], ahz[BM], ahn[BM];
    #pragma unroll
    for (int r = 0; r < BM; ++r) { air[r]=0.f; aiz[r]=0.f; ain[r]=0.f; ahr[r]=0.f; ahz[r]=0.f; ahn[r]=0.f; }

    const float4* __restrict__ wtI4 = (const float4*)wtI;
    const float4* __restrict__ wtH4 = (const float4*)wtH;

    for (int k4 = 0; k4 < INDIM / 4; ++k4) {
        float4 wir = wtI4[(k4 * 3 + 0) * HDIM + h];
        float4 wiz = wtI4[(k4 * 3 + 1) * HDIM + h];
        float4 win = wtI4[(k4 * 3 + 2) * HDIM + h];
        float4 whr = wtH4[(k4 * 3 + 0) * HDIM + h];
        float4 whz = wtH4[(k4 * 3 + 1) * HDIM + h];
        float4 whn = wtH4[(k4 * 3 + 2) * HDIM + h];
        #pragma unroll
        for (int r = 0; r < BM; ++r) {
            float4 xv = *(const float4*)(&xs[r][k4 * 4]);
            float4 sv = *(const float4*)(&ss[r][k4 * 4]);
            air[r] = fmaf(xv.w, wir.w, fmaf(xv.z, wir.z, fmaf(xv.y, wir.y, fmaf(xv.x, wir.x, air[r]))));
            aiz[r] = fmaf(xv.w, wiz.w, fmaf(xv.z, wiz.z, fmaf(xv.y, wiz.y, fmaf(xv.x, wiz.x, aiz[r]))));
            ain[r] = fmaf(xv.w, win.w, fmaf(xv.z, win.z, fmaf(xv.y, win.y, fmaf(xv.x, win.x, ain[r]))));
            ahr[r] = fmaf(sv.w, whr.w, fmaf(sv.z, whr.z, fmaf(sv.y, whr.y, fmaf(sv.x, whr.x, ahr[r]))));
            ahz[r] = fmaf(sv.w, whz.w, fmaf(sv.z, whz.z, fmaf(sv.y, whz.y, fmaf(sv.x, whz.x, ahz[r]))));
            ahn[r] = fmaf(sv.w, whn.w, fmaf(sv.z, whn.z, fmaf(sv.y, whn.y, fmaf(sv.x, whn.x, ahn[r]))));
        }
    }

    const float bir = b_ih[h], biz = b_ih[HDIM + h], bin = b_ih[2 * HDIM + h];
    const float bhr = b_hh[h], bhz = b_hh[HDIM + h], bhn = b_hh[2 * HDIM + h];

    #pragma unroll
    for (int r = 0; r < BM; ++r) {
        int g  = b0 + r;
        int bi = batch_idxs[g];
        int a  = actor_ids[bi];
        a = a < 0 ? 0 : (a > CAST - 1 ? CAST - 1 : a);
        float ir = air[r] + bir, iz = aiz[r] + biz, inn = ain[r] + bin;
        float hr = ahr[r] + bhr, hz = ahz[r] + bhz, hn = ahn[r] + bhn;
        float rr = 1.f / (1.f + __expf(-(ir + hr)));
        float zz = 1.f / (1.f + __expf(-(iz + hz)));
        float nn = tanhf(inn + rr * hn);
        float val = (1.f - zz) * nn + zz * ss[r][h];
        out_sel[(size_t)g * HDIM + h] = val;
        if (!rowstop[bi]) out_state[((size_t)bi * CAST + a) * HDIM + h] = val;
    }
}

// ---------------- lean streaming state copy ----------------
// One block per batch row (32 KB contiguous). aid/stop read once per block;
// all control is wave-uniform. 8-deep load batches for MLP; stop rows are
// pure fills (no read). Skips the (row, aid) slot — GRU wrote it.
__global__ __launch_bounds__(256) void k_copy(
    const float4* __restrict__ st4, const int* __restrict__ rowaid,
    const int* __restrict__ rowstop, float4* __restrict__ out4) {
    const int  b = blockIdx.x;
    const int  t = threadIdx.x;
    const long base = (long)b * ROW_F4;
    const int  aid = rowaid[b];

    if (rowstop[b]) {
        const float4 z = make_float4(0.f, 0.f, 0.f, 0.f);
        #pragma unroll
        for (int it = 0; it < ROW_F4 / 256; ++it)
            out4[base + it * 256 + t] = z;
        return;
    }

    #pragma unroll
    for (int g = 0; g < 4; ++g) {
        float4 d[8];
        #pragma unroll
        for (int i = 0; i < 8; ++i)
            d[i] = st4[base + (g * 8 + i) * 256 + t];
        #pragma unroll
        for (int i = 0; i < 8; ++i) {
            int idx = (g * 8 + i) * 256 + t;
            if ((idx >> 6) != aid)          // wave-uniform compare
                out4[base + idx] = d[i];
        }
    }
}

extern "C" void kernel_launch(void* const* d_in, const int* in_sizes, int n_in,
                              void* d_out, int out_size, void* d_ws, size_t ws_size,
                              hipStream_t stream) {
    const float* x          = (const float*)d_in[0];
    const int*   batch_idxs = (const int*)d_in[1];
    const int*   actor_ids  = (const int*)d_in[2];
    const int*   story_stop = (const int*)d_in[3];
    const float* state      = (const float*)d_in[4];
    const float* w_ih       = (const float*)d_in[5];
    const float* w_hh       = (const float*)d_in[6];
    const float* b_ih       = (const float*)d_in[7];
    const float* b_hh       = (const float*)d_in[8];
    const int    n_stop     = in_sizes[3];

    float* out_sel   = (float*)d_out;
    float* out_state = out_sel + (size_t)B_TOTAL * HDIM;

    int*   rowaid  = (int*)d_ws;
    int*   rowstop = rowaid + B_TOTAL;
    float* wtI     = (float*)((char*)d_ws + 16384);
    float* wtH     = wtI + (size_t)3 * HDIM * INDIM;

    k_init<<<(B_TOTAL + 255) / 256, 256, 0, stream>>>(rowaid, rowstop);
    k_prep<<<8 + 384, 256, 0, stream>>>(batch_idxs, actor_ids, story_stop, n_stop,
                                        w_ih, w_hh, rowaid, rowstop, wtI, wtH);
    k_gru<<<GRU_BLOCKS, 256, 0, stream>>>(x, batch_idxs, actor_ids, state,
                                          wtI, wtH, b_ih, b_hh, rowstop,
                                          out_sel, out_state);
    k_copy<<<B_TOTAL, 256, 0, stream>>>((const float4*)state, rowaid, rowstop,
                                        (float4*)out_state);
}

// Round 5
// 159.752 us; speedup vs baseline: 1.3372x; 1.3372x over previous
//
#include <hip/hip_runtime.h>

#define B_TOTAL 2048
#define CAST    128
#define HDIM    256
#define INDIM   256
#define BM      8
#define GRU_BLOCKS (B_TOTAL / BM)     // 256
#define ROW_F4     (CAST * HDIM / 4)  // 8192 float4 per batch row

typedef float fx4 __attribute__((ext_vector_type(4)));

// ---------------- tables init ----------------
__global__ __launch_bounds__(256) void k_init(int* rowaid, int* rowstop) {
    int t = blockIdx.x * blockDim.x + threadIdx.x;
    if (t < B_TOTAL) { rowaid[t] = -1; rowstop[t] = 0; }
}

// ---------------- fill tables + transpose weights ----------------
// blocks 0..7: fill rowaid/rowstop. blocks 8..391: pack weights as
// wt[((k4*3 + gate)*256 + h)*4 + j] = w[(gate*256 + h)*256 + k4*4 + j]
__global__ __launch_bounds__(256) void k_prep(
    const int* __restrict__ batch_idxs, const int* __restrict__ actor_ids,
    const int* __restrict__ story_stop, int n_stop,
    const float* __restrict__ w_ih, const float* __restrict__ w_hh,
    int* rowaid, int* rowstop, float* wtI, float* wtH) {
    const int h = threadIdx.x;
    if (blockIdx.x < 8) {
        int t = blockIdx.x * 256 + h;
        int row = batch_idxs[t];
        int a = actor_ids[row];
        a = a < 0 ? 0 : (a > CAST - 1 ? CAST - 1 : a);
        rowaid[row] = a;
        if (t < n_stop) rowstop[story_stop[t]] = 1;
    } else {
        int id  = blockIdx.x - 8;          // 0..383
        int mat = id / 192;                // 0: w_ih, 1: w_hh
        int rem = id % 192;
        int g   = rem / 64;
        int k4  = rem % 64;
        const float* w = mat ? w_hh : w_ih;
        float*      wt = mat ? wtH  : wtI;
        float4 wv = *(const float4*)(w + ((size_t)(g * HDIM + h) * INDIM + k4 * 4));
        *(float4*)(wt + ((size_t)((k4 * 3 + g) * HDIM + h)) * 4) = wv;
    }
}

// ---------------- fused GRU + lean state copy ----------------
// blocks [0, GRU_BLOCKS): GRU for BM rows each (writes out_sel + scatters
//   its slots into out_state unless stop). Weights/x cached normally.
// blocks [GRU_BLOCKS, GRU_BLOCKS + B_TOTAL): one batch row each —
//   nontemporal streaming copy state->out_state, zero stop rows,
//   scalar-branch skip of the (row, aid) slot.
__global__ __launch_bounds__(256) void k_main(
    const float* __restrict__ x, const int* __restrict__ batch_idxs,
    const int* __restrict__ actor_ids, const float* __restrict__ state,
    const float* __restrict__ wtI, const float* __restrict__ wtH,
    const float* __restrict__ b_ih, const float* __restrict__ b_hh,
    const int* __restrict__ rowaid, const int* __restrict__ rowstop,
    float* __restrict__ out_sel, float* __restrict__ out_state) {
    __shared__ float xs[BM][INDIM];
    __shared__ float ss[BM][HDIM];
    const int h = threadIdx.x;

    if (blockIdx.x < GRU_BLOCKS) {
        const int b0 = blockIdx.x * BM;
        #pragma unroll
        for (int r = 0; r < BM; ++r) {
            int g  = b0 + r;
            int bi = batch_idxs[g];
            int a  = actor_ids[bi];
            a = a < 0 ? 0 : (a > CAST - 1 ? CAST - 1 : a);
            xs[r][h] = x[(size_t)g * INDIM + h];
            ss[r][h] = state[((size_t)bi * CAST + a) * HDIM + h];
        }
        __syncthreads();

        float air[BM], aiz[BM], ain[BM], ahr[BM], ahz[BM], ahn[BM];
        #pragma unroll
        for (int r = 0; r < BM; ++r) { air[r]=0.f; aiz[r]=0.f; ain[r]=0.f; ahr[r]=0.f; ahz[r]=0.f; ahn[r]=0.f; }

        const float4* __restrict__ wtI4 = (const float4*)wtI;
        const float4* __restrict__ wtH4 = (const float4*)wtH;

        for (int k4 = 0; k4 < INDIM / 4; ++k4) {
            float4 wir = wtI4[(k4 * 3 + 0) * HDIM + h];
            float4 wiz = wtI4[(k4 * 3 + 1) * HDIM + h];
            float4 win = wtI4[(k4 * 3 + 2) * HDIM + h];
            float4 whr = wtH4[(k4 * 3 + 0) * HDIM + h];
            float4 whz = wtH4[(k4 * 3 + 1) * HDIM + h];
            float4 whn = wtH4[(k4 * 3 + 2) * HDIM + h];
            #pragma unroll
            for (int r = 0; r < BM; ++r) {
                float4 xv = *(const float4*)(&xs[r][k4 * 4]);
                float4 sv = *(const float4*)(&ss[r][k4 * 4]);
                air[r] = fmaf(xv.w, wir.w, fmaf(xv.z, wir.z, fmaf(xv.y, wir.y, fmaf(xv.x, wir.x, air[r]))));
                aiz[r] = fmaf(xv.w, wiz.w, fmaf(xv.z, wiz.z, fmaf(xv.y, wiz.y, fmaf(xv.x, wiz.x, aiz[r]))));
                ain[r] = fmaf(xv.w, win.w, fmaf(xv.z, win.z, fmaf(xv.y, win.y, fmaf(xv.x, win.x, ain[r]))));
                ahr[r] = fmaf(sv.w, whr.w, fmaf(sv.z, whr.z, fmaf(sv.y, whr.y, fmaf(sv.x, whr.x, ahr[r]))));
                ahz[r] = fmaf(sv.w, whz.w, fmaf(sv.z, whz.z, fmaf(sv.y, whz.y, fmaf(sv.x, whz.x, ahz[r]))));
                ahn[r] = fmaf(sv.w, whn.w, fmaf(sv.z, whn.z, fmaf(sv.y, whn.y, fmaf(sv.x, whn.x, ahn[r]))));
            }
        }

        const float bir = b_ih[h], biz = b_ih[HDIM + h], bin = b_ih[2 * HDIM + h];
        const float bhr = b_hh[h], bhz = b_hh[HDIM + h], bhn = b_hh[2 * HDIM + h];

        #pragma unroll
        for (int r = 0; r < BM; ++r) {
            int g  = b0 + r;
            int bi = batch_idxs[g];
            int a  = actor_ids[bi];
            a = a < 0 ? 0 : (a > CAST - 1 ? CAST - 1 : a);
            float ir = air[r] + bir, iz = aiz[r] + biz, inn = ain[r] + bin;
            float hr = ahr[r] + bhr, hz = ahz[r] + bhz, hn = ahn[r] + bhn;
            float rr = 1.f / (1.f + __expf(-(ir + hr)));
            float zz = 1.f / (1.f + __expf(-(iz + hz)));
            float nn = tanhf(inn + rr * hn);
            float val = (1.f - zz) * nn + zz * ss[r][h];
            out_sel[(size_t)g * HDIM + h] = val;
            if (!rowstop[bi]) out_state[((size_t)bi * CAST + a) * HDIM + h] = val;
        }
    } else {
        const int  b = blockIdx.x - GRU_BLOCKS;     // batch row
        const int  t = threadIdx.x;
        const long base = (long)b * ROW_F4;
        const fx4* __restrict__ src = (const fx4*)state + base + t;
        fx4* __restrict__ dst = (fx4*)out_state + base + t;

        if (rowstop[b]) {
            const fx4 z = (fx4)(0.f);
            #pragma unroll
            for (int j = 0; j < ROW_F4 / 256; ++j)
                __builtin_nontemporal_store(z, dst + j * 256);
            return;
        }

        // slot c of this row occupies idx>>6 == c; for thread t at iteration j,
        // c = j*4 + (t>>6).  Scalarize: each wave skips at most one iteration.
        const int aid = __builtin_amdgcn_readfirstlane(rowaid[b]);
        const int w   = __builtin_amdgcn_readfirstlane(t >> 6);
        const int jskip = ((aid & 3) == w) ? (aid >> 2) : -1;   // SGPR, -1 = none

        #pragma unroll
        for (int g2 = 0; g2 < 2; ++g2) {
            fx4 d[16];
            #pragma unroll
            for (int i = 0; i < 16; ++i)
                d[i] = __builtin_nontemporal_load(src + (g2 * 16 + i) * 256);
            #pragma unroll
            for (int i = 0; i < 16; ++i) {
                if (g2 * 16 + i != jskip)
                    __builtin_nontemporal_store(d[i], dst + (g2 * 16 + i) * 256);
            }
        }
    }
}

extern "C" void kernel_launch(void* const* d_in, const int* in_sizes, int n_in,
                              void* d_out, int out_size, void* d_ws, size_t ws_size,
                              hipStream_t stream) {
    const float* x          = (const float*)d_in[0];
    const int*   batch_idxs = (const int*)d_in[1];
    const int*   actor_ids  = (const int*)d_in[2];
    const int*   story_stop = (const int*)d_in[3];
    const float* state      = (const float*)d_in[4];
    const float* w_ih       = (const float*)d_in[5];
    const float* w_hh       = (const float*)d_in[6];
    const float* b_ih       = (const float*)d_in[7];
    const float* b_hh       = (const float*)d_in[8];
    const int    n_stop     = in_sizes[3];

    float* out_sel   = (float*)d_out;
    float* out_state = out_sel + (size_t)B_TOTAL * HDIM;

    int*   rowaid  = (int*)d_ws;
    int*   rowstop = rowaid + B_TOTAL;
    float* wtI     = (float*)((char*)d_ws + 16384);
    float* wtH     = wtI + (size_t)3 * HDIM * INDIM;

    k_init<<<(B_TOTAL + 255) / 256, 256, 0, stream>>>(rowaid, rowstop);
    k_prep<<<8 + 384, 256, 0, stream>>>(batch_idxs, actor_ids, story_stop, n_stop,
                                        w_ih, w_hh, rowaid, rowstop, wtI, wtH);
    k_main<<<GRU_BLOCKS + B_TOTAL, 256, 0, stream>>>(
        x, batch_idxs, actor_ids, state, wtI, wtH, b_ih, b_hh,
        rowaid, rowstop, out_sel, out_state);
}